// Round 15
// baseline (28.527 us; speedup 1.0000x reference)
//
#include <hip/hip_runtime.h>
#include <hip/hip_bf16.h>

// CP tensorized embedding gather via MFMA — r14 pipelined skeleton +
// operand-swapped MFMA + dwordx4 stores (8 store instrs/tile vs 32):
// out[t, e] = sum_r w[t,r] * B[r,e]
//   w[t,r] = U0[a,r]*U1[b,r]*U2[c,r], idx=x[t], a=idx/5000, b=(idx/50)%100, c=idx%50
//   B[r,e] = V0[e>>4,r]*V1[e&15,r]
// D = mfma(Btable, W): lane's 4 acc regs = 4 CONSECUTIVE e for one token.
// r13 priced store instructions at ~7cyc each => 32 scalar stores/tile is
// ~4.7us of budget; cut 4x. r3's dwordx4 test was confounded (serial
// front-end); this is the first dwordx4 test in the pipelined regime.

#define RANKK 32
#define EMB 128

typedef __attribute__((ext_vector_type(8))) short short8v;  // 8 bf16 = 4 VGPRs
typedef __attribute__((ext_vector_type(4))) float f32x4;

__device__ __forceinline__ short f2bf(float f) {
    union { __hip_bfloat16 h; short s; } u;
    u.h = __float2bfloat16(f);   // RNE
    return u.s;
}

struct G6 { float4 a0, a1, b0, b1, c0, c1; };

__device__ __forceinline__ G6 gather6(unsigned ui,
    const float* __restrict__ U0, const float* __restrict__ U1,
    const float* __restrict__ U2, int rb)
{
    const unsigned a   = ui / 5000u;
    const unsigned rem = ui - a * 5000u;
    const unsigned b   = rem / 50u;
    const unsigned c   = rem - b * 50u;
    const float4* p0 = (const float4*)(U0 + a * RANKK + rb);
    const float4* p1 = (const float4*)(U1 + b * RANKK + rb);
    const float4* p2 = (const float4*)(U2 + c * RANKK + rb);
    G6 r;
    r.a0 = p0[0]; r.a1 = p0[1];
    r.b0 = p1[0]; r.b1 = p1[1];
    r.c0 = p2[0]; r.c1 = p2[1];
    return r;
}

__device__ __forceinline__ short8v mkafrag(const G6& q) {
    float wv[8];
    wv[0]=q.a0.x*q.b0.x*q.c0.x; wv[1]=q.a0.y*q.b0.y*q.c0.y;
    wv[2]=q.a0.z*q.b0.z*q.c0.z; wv[3]=q.a0.w*q.b0.w*q.c0.w;
    wv[4]=q.a1.x*q.b1.x*q.c1.x; wv[5]=q.a1.y*q.b1.y*q.c1.y;
    wv[6]=q.a1.z*q.b1.z*q.c1.z; wv[7]=q.a1.w*q.b1.w*q.c1.w;
    short8v af;
    #pragma unroll
    for (int i = 0; i < 8; ++i) af[i] = f2bf(wv[i]);
    return af;
}

__global__ __launch_bounds__(256) void cpemb_mfma(
    const int* __restrict__ x,
    const float* __restrict__ U0, const float* __restrict__ U1,
    const float* __restrict__ U2,
    const float* __restrict__ V0, const float* __restrict__ V1,
    float* __restrict__ out, int ntok)
{
    const int tid  = threadIdx.x;
    const int lane = tid & 63;
    const int gw   = blockIdx.x * 4 + (tid >> 6);
    const int nw   = gridDim.x * 4;
    const int ngroups = (ntok + 15) >> 4;   // 16-token tiles

    const int t_l = lane & 15;   // token-within-tile (B-operand n) == D col
    const int g   = lane >> 4;   // k-chunk group; D row block (g*4+j)
    const int rb  = g * 8;       // rank base (k = rb..rb+7)

    if (gw >= ngroups) return;

    // ---- loop-invariant table fragments (the MFMA *A* operand, swapped):
    // m = e_in_block = t_l -> V1 row = t_l; V0 row = eb (lane-uniform).
    float v1r[8];
    {
        const float4* p = (const float4*)(V1 + t_l * RANKK + rb);
        float4 lo = p[0], hi = p[1];
        v1r[0]=lo.x; v1r[1]=lo.y; v1r[2]=lo.z; v1r[3]=lo.w;
        v1r[4]=hi.x; v1r[5]=hi.y; v1r[6]=hi.z; v1r[7]=hi.w;
    }
    short8v bfrag[8];
    #pragma unroll
    for (int eb = 0; eb < 8; ++eb) {
        const float4* p = (const float4*)(V0 + eb * RANKK + rb);
        float4 lo = p[0], hi = p[1];
        float v0r[8] = {lo.x, lo.y, lo.z, lo.w, hi.x, hi.y, hi.z, hi.w};
        #pragma unroll
        for (int i = 0; i < 8; ++i)
            bfrag[eb][i] = f2bf(v0r[i] * v1r[i]);
    }

    // ---- prologue: x + gathers for tile gw; x for tile gw+nw ----
    G6 gcur;
    {
        int tok = (gw << 4) + t_l;
        if (tok >= ntok) tok = ntok - 1;
        gcur = gather6((unsigned)x[tok], U0, U1, U2, rb);
    }
    unsigned ui_n = 0u;
    if (gw + nw < ngroups) {
        int tn = ((gw + nw) << 4) + t_l;
        if (tn >= ntok) tn = ntok - 1;
        ui_n = (unsigned)x[tn];
    }

    for (int grp = gw; grp < ngroups; grp += nw) {
        // ---- W-fragment for current tile (waits only on gcur's loads)
        short8v afrag = mkafrag(gcur);

        // ---- pipeline refill, issued BEFORE this tile's stores ----
        const int  gnx = grp + nw;
        const bool hn  = gnx < ngroups;
        G6 gn;
        if (hn) gn = gather6(ui_n, U0, U1, U2, rb);
        const int gn2 = grp + 2 * nw;
        if (gn2 < ngroups) {
            int t2 = (gn2 << 4) + t_l;
            if (t2 >= ntok) t2 = ntok - 1;
            ui_n = (unsigned)x[t2];
        }

        // ---- 8 swapped MFMAs: D[m=e_in_block, n=token]; lane = one token,
        // 4 contiguous e per acc -> one global_store_dwordx4 each.
        const int t0  = grp << 4;
        const bool ok = (t0 + t_l) < ntok;
        float* orow = out + (size_t)(t0 + t_l) * EMB + g * 4;
        #pragma unroll
        for (int eb = 0; eb < 8; ++eb) {
            f32x4 z = {0.f, 0.f, 0.f, 0.f};
            f32x4 acc = __builtin_amdgcn_mfma_f32_16x16x32_bf16(bfrag[eb], afrag, z, 0, 0, 0);
            if (ok)
                *(f32x4*)(orow + eb * 16) = acc;   // global_store_dwordx4
        }

        if (hn) gcur = gn;
    }
}

extern "C" void kernel_launch(void* const* d_in, const int* in_sizes, int n_in,
                              void* d_out, int out_size, void* d_ws, size_t ws_size,
                              hipStream_t stream) {
    const int*   x  = (const int*)d_in[0];
    const float* U0 = (const float*)d_in[1];
    const float* U1 = (const float*)d_in[2];
    const float* U2 = (const float*)d_in[3];
    const float* V0 = (const float*)d_in[4];
    const float* V1 = (const float*)d_in[5];
    float* out = (float*)d_out;

    const int ntok = in_sizes[0];   // 204800 -> 12800 tiles
    // 768 blocks = 3072 waves -> ~4.2 tiles/wave, 3 waves/SIMD residency.
    const int blocks = 768;

    cpemb_mfma<<<blocks, 256, 0, stream>>>(x, U0, U1, U2, V0, V1, out, ntok);
}